// Round 1
// baseline (58340.814 us; speedup 1.0000x reference)
//
#include <hip/hip_runtime.h>
#include <stdint.h>
#include <stddef.h>

// ACT-LSTM, B=32 T=512 IN=50 H=512 OUT=66, MAX_PONDER=10, EPS=0.01, fp32.
// Strategy: persistent cooperative kernel, 256 blocks x 256 threads (1 block/CU).
// One grid barrier per cell step ("phase"); halt recomputed per-block
// (deterministic, no atomics). Output projection + segment softmax deferred to a
// parallel epilogue via linearity (sum p = 1).

#define NBLK 256

// ---------------- ws layout (float offsets) ----------------
// wh   : [0, 8388608)            512*32*512  (32 MB)   weighted h per timestep
// hbuf : [8388608, 8421376)      2*16384     h ping-pong (packed [k4][b*4+kl])
// bar  : [8421376, 8421632)      barrier counters (1 KB)
// W_r4 : [8421632, 9470208)      1048576     W_hh repacked [k4][j*16+g*4+kl]
// W_iT : [9470208, 9574656)      51*2048     W_ih repacked [k][j*4+g]
// W_oT : [9574656, 9608448)      512*66      W_out transposed [k][o]
#define WS_NEED_BYTES 38433792ull

__device__ __forceinline__ float sigmf(float v) { return 1.0f / (1.0f + expf(-v)); }

#if defined(__has_builtin)
#if __has_builtin(__builtin_amdgcn_global_load_lds)
#define HAVE_GLLDS 1
#endif
#endif

__device__ __forceinline__ void stage_instr(const float* gp, float* lp) {
#ifdef HAVE_GLLDS
  // 16 B per lane, LDS dest = wave-uniform base + lane*16
  __builtin_amdgcn_global_load_lds((const __attribute__((address_space(1))) unsigned int*)gp,
                                   (__attribute__((address_space(3))) unsigned int*)lp,
                                   16, 0, 0);
#else
  const int lane = threadIdx.x & 63;
  *(float4*)(lp + lane * 4) = *(const float4*)(gp);
#endif
}

// ------------------------------------------------------------------
// prep: repack weights into k-major layouts so each wave's per-k4 load
// is one contiguous 128B line.
__global__ void prep_k(const float* __restrict__ W_ih, const float* __restrict__ W_hh,
                       const float* __restrict__ W_out,
                       float* __restrict__ W_r4, float* __restrict__ W_iT,
                       float* __restrict__ W_oT) {
  int idx = blockIdx.x * 256 + threadIdx.x;
  if (idx < 1048576) {
    int kl = idx & 3, g = (idx >> 2) & 3, j = (idx >> 4) & 511, k4 = idx >> 13;
    W_r4[idx] = W_hh[(size_t)((g << 9) + j) * 512 + (k4 << 2) + kl];
  }
  int i2 = idx - 1048576;
  if (i2 >= 0 && i2 < 104448) {
    int col = i2 & 2047, k = i2 >> 11;
    int g = col & 3, j = col >> 2;
    W_iT[i2] = W_ih[(size_t)((g << 9) + j) * 51 + k];
  }
  int i3 = idx - 1153024;
  if (i3 >= 0 && i3 < 33792) {
    int k = i3 / 66, o = i3 - k * 66;
    W_oT[i3] = W_out[(size_t)o * 512 + k];
  }
}

// ------------------------------------------------------------------
// persistent ACT-LSTM kernel
__global__ void __launch_bounds__(256)
act_main(const float* __restrict__ x, const float* __restrict__ bvec,
         const float* __restrict__ W_halt, const float* __restrict__ b_halt,
         const float* __restrict__ W_r4, const float* __restrict__ W_iT,
         float* __restrict__ hbuf, unsigned* __restrict__ bar,
         float* __restrict__ wh, float* __restrict__ p_out) {
  __shared__ float hch[2][4096];     // h staging chunks (128 k x 32 b each)
  __shared__ float xch[256];         // gate exchange
  __shared__ float hps[256];         // halt partials
  __shared__ float S_cum[32], S_p[32], S_nupd[32], S_rem[32];
  __shared__ int S_done[32];
  __shared__ int S_scal[4];          // t, n, noact, alldone

  const int tid = threadIdx.x, bid = blockIdx.x;
  const int b_i = tid >> 3, sub = tid & 7, jl = sub & 1, gate = sub >> 1;
  const int j = bid * 2 + jl;                 // this thread's j (0..511)
  const int offw = j * 16 + gate * 4;         // dword offset in W_r4 k4-row
  const int offi = j * 4 + gate;              // dword offset in W_iT k-row
  const int r = gate * 512 + j;               // row in [4H]
  const int wid = tid >> 6, lane4 = (tid & 63) * 4;
  const int hoidx = (j >> 2) * 128 + b_i * 4 + (j & 3);  // packed h index (k=j)
  const int klh = sub >> 1, lkp = sub & 1;    // halt-slice mapping (bank-friendly)

  const float bias = bvec[r];
  const float bh = b_halt[0];

  if (tid < 32) { S_cum[tid] = 0.f; S_done[tid] = 0; S_nupd[tid] = 0.f; S_rem[tid] = 0.f; }
  if (tid == 0) { S_scal[0] = 0; S_scal[1] = 0; S_scal[2] = 1; S_scal[3] = 0; }
  float cS = 0.f, hprev = 0.f, acc_h = 0.f, acc_c = 0.f, gxb = 0.f, wfl = 0.f;
  int sp = 0;
  __syncthreads();

  while (true) {
    const int t = S_scal[0], n = S_scal[1], noact = S_scal[2];
    const float* hin = hbuf + sp * 16384;
    float* hout = hbuf + (sp ^ 1) * 16384;

    if (n == 0) {  // per-timestep x contribution (kept in registers)
      gxb = bias;
      const float* xr = x + ((size_t)b_i * 512 + t) * 50;
      for (int k = 0; k < 50; ++k) gxb = fmaf(xr[k], W_iT[k * 2048 + offi], gxb);
      wfl = W_iT[50 * 2048 + offi];  // first-step flag column
    }

    float a0 = gxb + (n == 0 ? wfl : 0.f), a1 = 0.f, a2 = 0.f, a3 = 0.f;
    float hpart = 0.f;

    // stage chunk 0
    {
      const float* gp = hin + lane4 + wid * 1024;
      float* lp = &hch[0][wid * 1024];
      stage_instr(gp, lp); stage_instr(gp + 256, lp + 256);
      stage_instr(gp + 512, lp + 512); stage_instr(gp + 768, lp + 768);
    }
    for (int c = 0; c < 4; ++c) {
      asm volatile("s_waitcnt vmcnt(0)" ::: "memory");
      __syncthreads();                       // all waves' chunk c staged
      if (c < 3) {                           // prefetch next chunk (async DMA)
        const float* gp = hin + (c + 1) * 4096 + lane4 + wid * 1024;
        float* lp = &hch[(c + 1) & 1][wid * 1024];
        stage_instr(gp, lp); stage_instr(gp + 256, lp + 256);
        stage_instr(gp + 512, lp + 512); stage_instr(gp + 768, lp + 768);
      }
      const float* hl = hch[c & 1];
      const float* hb = hl + b_i * 4;
      const float* wb = W_r4 + (size_t)c * 32 * 8192 + offw;
      #pragma unroll 8
      for (int u = 0; u < 32; ++u) {         // 128 k per chunk, 4 fmac chains
        const float4 h4 = *(const float4*)(hb + u * 128);
        const float4 w4 = *(const float4*)(wb + (size_t)u * 8192);
        a0 = fmaf(h4.x, w4.x, a0);
        a1 = fmaf(h4.y, w4.y, a1);
        a2 = fmaf(h4.z, w4.z, a2);
        a3 = fmaf(h4.w, w4.w, a3);
      }
      // halt partial for this block's replicated halt dot (input h = h2 of prev step)
      const float* whp = W_halt + c * 128;
      #pragma unroll
      for (int it = 0; it < 16; ++it) {
        const int lk4 = it * 2 + lkp;
        hpart = fmaf(hl[lk4 * 128 + b_i * 4 + klh], whp[lk4 * 4 + klh], hpart);
      }
    }
    const float acc = (a0 + a1) + (a2 + a3);
    xch[tid] = acc; hps[tid] = hpart;
    __syncthreads();

    float c_new = 0.f, h_new = 0.f;
    if (sub < 2) {  // owner of (b_i, j): combine gates, write h2 (speculative)
      const float gi = xch[b_i * 8 + jl];
      const float gf = xch[b_i * 8 + 2 + jl];
      const float gg = xch[b_i * 8 + 4 + jl];
      const float go = xch[b_i * 8 + 6 + jl];
      c_new = sigmf(gf) * cS + sigmf(gi) * tanhf(gg);
      h_new = sigmf(go) * tanhf(c_new);
      hout[hoidx] = h_new;
    }

    int carry = 0;
    if (!noact) {  // ACT bookkeeping for step n-1 (its h2 is the staged input)
      if (tid < 32) {
        const float* q = hps + tid * 8;
        const float d = ((q[0] + q[1]) + (q[2] + q[3])) + ((q[4] + q[5]) + (q[6] + q[7]));
        const float halt = sigmf(d + bh);
        const float cum = S_cum[tid];
        const int done = S_done[tid];
        const int halted = ((cum + halt) > 0.99f) || ((n - 1) == 9);
        const float p = done ? 0.f : (halted ? (1.f - cum) : halt);
        S_p[tid] = p;
        S_nupd[tid] += done ? 0.f : 1.f;
        S_rem[tid] += (done || !halted) ? 0.f : (1.f - cum);
        S_cum[tid] = cum + (done ? 0.f : halt);
        S_done[tid] = done | halted;
      }
      __syncthreads();
      if (tid == 0) {
        int ad = 1;
        for (int i = 0; i < 32; ++i) ad &= S_done[i];
        S_scal[3] = ad;
      }
      __syncthreads();
      carry = S_scal[3];
      if (sub < 2) {
        const float p = S_p[b_i];
        acc_h = fmaf(p, hprev, acc_h);   // h2 of step n-1
        acc_c = fmaf(p, cS, acc_c);      // c2 of step n-1
      }
    }

    if (carry) {  // timestep ends: discard speculative step, emit carry
      if (sub < 2) {
        hout[hoidx] = acc_h;                                   // carry h -> next input
        wh[(size_t)t * 16384 + (size_t)b_i * 512 + j] = acc_h; // for epilogue
        cS = acc_c; acc_h = 0.f; acc_c = 0.f;
      }
      if (bid == 0 && tid < 32)
        p_out[(size_t)tid * 512 + t] = S_nupd[tid] + S_rem[tid];
      __syncthreads();
      if (tid < 32) { S_cum[tid] = 0.f; S_done[tid] = 0; S_nupd[tid] = 0.f; S_rem[tid] = 0.f; }
      if (tid == 0) { S_scal[0] = t + 1; S_scal[1] = 0; S_scal[2] = 1; }
      if (t + 1 == 512) break;
    } else {      // commit cell step n
      if (sub < 2) { cS = c_new; hprev = h_new; }
      if (tid == 0) { S_scal[1] = n + 1; S_scal[2] = 0; }
    }

    sp ^= 1;
    // ---- grid barrier: 2-level (8 groups x 32) + generation spin ----
    __syncthreads();
    if (tid == 0) {
      __threadfence();  // release: h2/acc stores visible device-wide
      const unsigned g = __hip_atomic_load(&bar[144], __ATOMIC_RELAXED, __HIP_MEMORY_SCOPE_AGENT);
      const int grp = bid & 7;
      const unsigned a = __hip_atomic_fetch_add(&bar[grp * 16], 1u, __ATOMIC_ACQ_REL, __HIP_MEMORY_SCOPE_AGENT);
      if (a == 31u) {
        __hip_atomic_store(&bar[grp * 16], 0u, __ATOMIC_RELAXED, __HIP_MEMORY_SCOPE_AGENT);
        const unsigned a2 = __hip_atomic_fetch_add(&bar[128], 1u, __ATOMIC_ACQ_REL, __HIP_MEMORY_SCOPE_AGENT);
        if (a2 == 7u) {
          __hip_atomic_store(&bar[128], 0u, __ATOMIC_RELAXED, __HIP_MEMORY_SCOPE_AGENT);
          __hip_atomic_store(&bar[144], g + 1u, __ATOMIC_RELEASE, __HIP_MEMORY_SCOPE_AGENT);
        }
      }
      while (__hip_atomic_load(&bar[144], __ATOMIC_RELAXED, __HIP_MEMORY_SCOPE_AGENT) == g)
        __builtin_amdgcn_s_sleep(1);
      __threadfence();  // acquire: invalidate stale L1/L2 before reading new h
    }
    __syncthreads();
  }
}

// ------------------------------------------------------------------
// epilogue: out[b,t,:] = seg-softmax(wh[t,b,:] @ W_out^T + b_out)
// 4 (b,t) pairs per 256-thread block; 33 active lanes x 2 outputs each.
__global__ void __launch_bounds__(256)
epi_k(const float* __restrict__ wh, const float* __restrict__ W_oT,
      const float* __restrict__ b_out, float* __restrict__ out) {
  __shared__ float hl[4][512];
  __shared__ float yl[4][66];
  const int tid = threadIdx.x, pair = tid >> 6, lane = tid & 63;
  const int bt = blockIdx.x * 4 + pair;
  const int b = bt >> 9, t = bt & 511;
  const float* hsrc = wh + (size_t)t * 16384 + (size_t)b * 512;
  *(float4*)&hl[pair][lane * 8] = *(const float4*)(hsrc + lane * 8);
  *(float4*)&hl[pair][lane * 8 + 4] = *(const float4*)(hsrc + lane * 8 + 4);
  __syncthreads();
  if (lane < 33) {
    const int o = lane * 2;
    float y0 = b_out[o], y1 = b_out[o + 1];
    const float* hp_ = hl[pair];
    #pragma unroll 8
    for (int k = 0; k < 512; ++k) {
      const float h = hp_[k];
      const float2 w = *(const float2*)(W_oT + k * 66 + o);
      y0 = fmaf(h, w.x, y0);
      y1 = fmaf(h, w.y, y1);
    }
    yl[pair][o] = y0; yl[pair][o + 1] = y1;
  }
  __syncthreads();
  if (tid < 24) {
    const int pr = tid / 6, g = tid - pr * 6;
    const int bt2 = blockIdx.x * 4 + pr;
    const float* yp = &yl[pr][g * 11];
    float m = yp[0];
    for (int u = 1; u < 11; ++u) m = fmaxf(m, yp[u]);
    float e[11], ssum = 0.f;
    for (int u = 0; u < 11; ++u) { e[u] = expf(yp[u] - m); ssum += e[u]; }
    const float inv = 1.0f / ssum;
    float* op = out + (size_t)bt2 * 66 + g * 11;
    for (int u = 0; u < 11; ++u) op[u] = e[u] * inv;
  }
}

// ------------------------------------------------------------------
extern "C" void kernel_launch(void* const* d_in, const int* in_sizes, int n_in,
                              void* d_out, int out_size, void* d_ws, size_t ws_size,
                              hipStream_t stream) {
  (void)in_sizes; (void)n_in; (void)out_size;
  const float* x      = (const float*)d_in[0];
  const float* W_ih   = (const float*)d_in[1];
  const float* W_hh   = (const float*)d_in[2];
  const float* bvec   = (const float*)d_in[3];
  const float* W_out  = (const float*)d_in[4];
  const float* b_out  = (const float*)d_in[5];
  const float* W_halt = (const float*)d_in[6];
  const float* b_halt = (const float*)d_in[7];
  float* out = (float*)d_out;
  float* ws  = (float*)d_ws;

  if (ws_size < (size_t)WS_NEED_BYTES) return;  // visible failure if ws too small

  float* wh    = ws;
  float* hbuf  = ws + 8388608;
  unsigned* bar = (unsigned*)(ws + 8421376);
  float* W_r4  = ws + 8421632;
  float* W_iT  = ws + 9470208;
  float* W_oT  = ws + 9574656;
  float* p_out = out + 1081344;  // B*T*OUT

  // zero h ping-pong + barrier state (ws is poisoned 0xAA before each call)
  hipMemsetAsync((void*)hbuf, 0, (32768 + 256) * 4, stream);
  hipLaunchKernelGGL(prep_k, dim3(4637), dim3(256), 0, stream,
                     W_ih, W_hh, W_out, W_r4, W_iT, W_oT);

  void* args[10];
  args[0] = (void*)&x;      args[1] = (void*)&bvec;  args[2] = (void*)&W_halt;
  args[3] = (void*)&b_halt; args[4] = (void*)&W_r4;  args[5] = (void*)&W_iT;
  args[6] = (void*)&hbuf;   args[7] = (void*)&bar;   args[8] = (void*)&wh;
  args[9] = (void*)&p_out;
  hipLaunchCooperativeKernel((void*)act_main, dim3(NBLK), dim3(256), args, 0, stream);

  hipLaunchKernelGGL(epi_k, dim3(4096), dim3(256), 0, stream, wh, W_oT, b_out, out);
}

// Round 2
// 29692.981 us; speedup vs baseline: 1.9648x; 1.9648x over previous
//
#include <hip/hip_runtime.h>
#include <stdint.h>
#include <stddef.h>

// ACT-LSTM, B=32 T=512 IN=50 H=512 OUT=66, MAX_PONDER=10, EPS=0.01, fp32.
// Round 2: selective coherence. No agent fences (no L2 wb/inv!). Only the h
// ping-pong + barrier words are LLC-coherent (sc0 sc1 ops / relaxed agent
// atomics); weights stay warm in L1/L2 across all phases. 128 blocks.

#define NBLK 128

// ---------------- ws layout (float offsets) ----------------
// wh   : [0, 8388608)            512*32*512  (32 MB)
// hbuf : [8388608, 8421376)      2*16384     h ping-pong (packed [k4][b*4+kl])
// bar  : [8421376, 8421632)      barrier counters (1 KB)
// W_r4 : [8421632, 9470208)      1048576     W_hh repacked [k4][j*16+g*4+kl]
// W_iT : [9470208, 9574656)      51*2048     W_ih repacked [k][j*4+g]
// W_oT : [9574656, 9608448)      512*66      W_out transposed [k][o]
#define WS_NEED_BYTES 38433792ull

__device__ __forceinline__ float sigmf(float v) { return 1.0f / (1.0f + expf(-v)); }

// LLC-coherent (cross-XCD) store: bypass L1+L2 (sc0 sc1), lands at MALL.
__device__ __forceinline__ void store_llc(float* p, float v) {
  asm volatile("global_store_dword %0, %1, off sc0 sc1" :: "v"(p), "v"(v) : "memory");
}

#if defined(__has_builtin)
#if __has_builtin(__builtin_amdgcn_global_load_lds)
#define HAVE_GLLDS 1
#endif
#endif

// LLC-coherent global->LDS DMA, 16 B/lane. aux=0x11 = SC0|SC1 (LLVM CPol:
// GLC=1 -> sc0, SCC=16 -> sc1 on gfx940+): bypass L1+L2, read coherence point.
__device__ __forceinline__ void stage_instr(const float* gp, float* lp) {
#ifdef HAVE_GLLDS
  __builtin_amdgcn_global_load_lds((const __attribute__((address_space(1))) unsigned int*)gp,
                                   (__attribute__((address_space(3))) unsigned int*)lp,
                                   16, 0, 0x11);
#else
  float4 tmp;
  asm volatile("global_load_dwordx4 %0, %1, off sc0 sc1" : "=v"(tmp) : "v"(gp) : "memory");
  asm volatile("s_waitcnt vmcnt(0)" ::: "memory");
  *(float4*)(lp + (threadIdx.x & 63) * 4) = tmp;
#endif
}

// ------------------------------------------------------------------
// prep: repack weights (k-major) + zero hbuf/bar. Kernel-end release flushes
// L2 so the zeros are visible to act_main's LLC-point reads/atomics.
__global__ void prep_k(const float* __restrict__ W_ih, const float* __restrict__ W_hh,
                       const float* __restrict__ W_out,
                       float* __restrict__ W_r4, float* __restrict__ W_iT,
                       float* __restrict__ W_oT, float* __restrict__ hbuf,
                       unsigned* __restrict__ bar) {
  int idx = blockIdx.x * 256 + threadIdx.x;
  if (idx < 1048576) {
    int kl = idx & 3, g = (idx >> 2) & 3, j = (idx >> 4) & 511, k4 = idx >> 13;
    W_r4[idx] = W_hh[(size_t)((g << 9) + j) * 512 + (k4 << 2) + kl];
  }
  int i2 = idx - 1048576;
  if (i2 >= 0 && i2 < 104448) {
    int col = i2 & 2047, k = i2 >> 11;
    int g = col & 3, j = col >> 2;
    W_iT[i2] = W_ih[(size_t)((g << 9) + j) * 51 + k];
  }
  int i3 = idx - 1153024;
  if (i3 >= 0 && i3 < 33792) {
    int k = i3 / 66, o = i3 - k * 66;
    W_oT[i3] = W_out[(size_t)o * 512 + k];
  }
  int i4 = idx - 1186816;
  if (i4 >= 0 && i4 < 33024) {
    if (i4 < 32768) hbuf[i4] = 0.0f;
    else bar[i4 - 32768] = 0u;
  }
}

// ------------------------------------------------------------------
// persistent ACT-LSTM kernel: 128 blocks x 256 threads, 4 j-columns per block,
// 2 dot-products (512-K each) per thread per phase.
__global__ void __launch_bounds__(256)
act_main(const float* __restrict__ x, const float* __restrict__ bvec,
         const float* __restrict__ W_halt, const float* __restrict__ b_halt,
         const float* __restrict__ W_r4, const float* __restrict__ W_iT,
         float* __restrict__ hbuf, unsigned* __restrict__ bar,
         float* __restrict__ wh, float* __restrict__ p_out) {
  __shared__ float hch[2][4096];     // h staging chunks (128 k x 32 b each)
  __shared__ float xch[2][256];      // gate exchange (2 j-halves)
  __shared__ float hps[256];         // halt partials
  __shared__ float S_cum[32], S_p[32], S_nupd[32], S_rem[32];
  __shared__ int S_done[32];
  __shared__ int S_scal[4];          // t, n, noact, alldone

  const int tid = threadIdx.x, bid = blockIdx.x;
  const int b_i = tid >> 3, sub = tid & 7, jl = sub & 1, gate = sub >> 1;
  const int ja = bid * 4 + jl;                // first j of this thread
  const int offw_a = ja * 16 + gate * 4;      // W_r4 dword offset (j_a); j_b = +32
  const int offi_a = ja * 4 + gate;           // W_iT dword offset (j_a); j_b = +8
  const int wid = tid >> 6, lane4 = (tid & 63) * 4;
  const int klh = sub >> 1, lkp = sub & 1;    // halt-slice mapping

  const float bias_a = bvec[gate * 512 + ja];
  const float bias_b = bvec[gate * 512 + ja + 2];
  const float bh = b_halt[0];

  // owner lane (sub<4): owns (b_i, j = 4*bid + sub)
  const int own_s = sub;
  const int hoidx = bid * 128 + b_i * 4 + own_s;

  if (tid < 32) { S_cum[tid] = 0.f; S_done[tid] = 0; S_nupd[tid] = 0.f; S_rem[tid] = 0.f; }
  if (tid == 0) { S_scal[0] = 0; S_scal[1] = 0; S_scal[2] = 1; S_scal[3] = 0; }
  float cS = 0.f, hprev = 0.f, acc_h = 0.f, acc_c = 0.f;
  float gxa = 0.f, gxb2 = 0.f, wfa = 0.f, wfb = 0.f;
  int sp = 0;
  __syncthreads();

  while (true) {
    const int t = S_scal[0], n = S_scal[1], noact = S_scal[2];
    const float* hin = hbuf + sp * 16384;
    float* hout = hbuf + (sp ^ 1) * 16384;

    // issue chunk-0 DMA first so it overlaps the x-projection below
    {
      const float* gp = hin + lane4 + wid * 1024;
      float* lp = &hch[0][wid * 1024];
      stage_instr(gp, lp); stage_instr(gp + 256, lp + 256);
      stage_instr(gp + 512, lp + 512); stage_instr(gp + 768, lp + 768);
    }

    if (n == 0) {  // per-timestep x contribution (cached loads, stays warm)
      gxa = bias_a; gxb2 = bias_b;
      const float* xr = x + ((size_t)b_i * 512 + t) * 50;
      for (int k = 0; k < 50; ++k) {
        const float xv = xr[k];
        gxa  = fmaf(xv, W_iT[k * 2048 + offi_a], gxa);
        gxb2 = fmaf(xv, W_iT[k * 2048 + offi_a + 8], gxb2);
      }
      wfa = W_iT[50 * 2048 + offi_a];      // first-step flag column
      wfb = W_iT[50 * 2048 + offi_a + 8];
    }

    float a0 = gxa + (n == 0 ? wfa : 0.f), a1 = 0.f, a2 = 0.f, a3 = 0.f;
    float b0 = gxb2 + (n == 0 ? wfb : 0.f), b1 = 0.f, b2 = 0.f, b3 = 0.f;
    float hpart = 0.f;

    for (int c = 0; c < 4; ++c) {
      asm volatile("s_waitcnt vmcnt(0)" ::: "memory");
      __syncthreads();                       // all waves' chunk c staged
      if (c < 3) {                           // prefetch next chunk (async DMA)
        const float* gp = hin + (c + 1) * 4096 + lane4 + wid * 1024;
        float* lp = &hch[(c + 1) & 1][wid * 1024];
        stage_instr(gp, lp); stage_instr(gp + 256, lp + 256);
        stage_instr(gp + 512, lp + 512); stage_instr(gp + 768, lp + 768);
      }
      const float* hl = hch[c & 1];
      const float* hb = hl + b_i * 4;
      const float* wb = W_r4 + (size_t)c * 32 * 8192 + offw_a;
      #pragma unroll 4
      for (int u = 0; u < 32; ++u) {         // 128 k per chunk, 2 dots/thread
        const float4 h4 = *(const float4*)(hb + u * 128);
        const float4 wa = *(const float4*)(wb + (size_t)u * 8192);
        const float4 wc = *(const float4*)(wb + (size_t)u * 8192 + 32);
        a0 = fmaf(h4.x, wa.x, a0); a1 = fmaf(h4.y, wa.y, a1);
        a2 = fmaf(h4.z, wa.z, a2); a3 = fmaf(h4.w, wa.w, a3);
        b0 = fmaf(h4.x, wc.x, b0); b1 = fmaf(h4.y, wc.y, b1);
        b2 = fmaf(h4.z, wc.z, b2); b3 = fmaf(h4.w, wc.w, b3);
      }
      // halt partial for the replicated per-block halt dot (input = staged h)
      const float* whp = W_halt + c * 128;
      #pragma unroll
      for (int it = 0; it < 16; ++it) {
        const int lk4 = it * 2 + lkp;
        hpart = fmaf(hl[lk4 * 128 + b_i * 4 + klh], whp[lk4 * 4 + klh], hpart);
      }
    }
    xch[0][tid] = (a0 + a1) + (a2 + a3);
    xch[1][tid] = (b0 + b1) + (b2 + b3);
    hps[tid] = hpart;
    __syncthreads();

    float c_new = 0.f, h_new = 0.f;
    if (sub < 4) {  // owner of (b_i, 4*bid+sub): combine gates
      const int jjl = own_s & 1;
      const float* arr = (own_s < 2) ? xch[0] : xch[1];
      const float gi = arr[b_i * 8 + jjl];
      const float gf = arr[b_i * 8 + 2 + jjl];
      const float gg = arr[b_i * 8 + 4 + jjl];
      const float go = arr[b_i * 8 + 6 + jjl];
      c_new = sigmf(gf) * cS + sigmf(gi) * tanhf(gg);
      h_new = sigmf(go) * tanhf(c_new);
    }

    int carry = 0;
    if (!noact) {  // ACT bookkeeping for step n-1 (its h2 is the staged input)
      if (tid < 32) {
        const float* q = hps + tid * 8;
        const float d = ((q[0] + q[1]) + (q[2] + q[3])) + ((q[4] + q[5]) + (q[6] + q[7]));
        const float halt = sigmf(d + bh);
        const float cum = S_cum[tid];
        const int done = S_done[tid];
        const int halted = ((cum + halt) > 0.99f) || ((n - 1) == 9);
        const float p = done ? 0.f : (halted ? (1.f - cum) : halt);
        S_p[tid] = p;
        S_nupd[tid] += done ? 0.f : 1.f;
        S_rem[tid] += (done || !halted) ? 0.f : (1.f - cum);
        S_cum[tid] = cum + (done ? 0.f : halt);
        S_done[tid] = done | halted;
      }
      __syncthreads();
      if (tid == 0) {
        int ad = 1;
        for (int i = 0; i < 32; ++i) ad &= S_done[i];
        S_scal[3] = ad;
      }
      __syncthreads();
      carry = S_scal[3];
      if (sub < 4) {
        const float p = S_p[b_i];
        acc_h = fmaf(p, hprev, acc_h);   // h2 of step n-1
        acc_c = fmaf(p, cS, acc_c);      // c2 of step n-1
      }
    }

    if (carry) {  // timestep ends: discard speculative step, emit carry
      if (sub < 4) {
        store_llc(&hout[hoidx], acc_h);                        // carry -> next input
        wh[(size_t)t * 16384 + (size_t)b_i * 512 + bid * 4 + own_s] = acc_h;
        cS = acc_c; acc_h = 0.f; acc_c = 0.f;
      }
      if (bid == 0 && tid < 32)
        p_out[(size_t)tid * 512 + t] = S_nupd[tid] + S_rem[tid];
      __syncthreads();
      if (tid < 32) { S_cum[tid] = 0.f; S_done[tid] = 0; S_nupd[tid] = 0.f; S_rem[tid] = 0.f; }
      if (tid == 0) { S_scal[0] = t + 1; S_scal[1] = 0; S_scal[2] = 1; }
      if (t + 1 == 512) break;
    } else {      // commit cell step n
      if (sub < 4) {
        store_llc(&hout[hoidx], h_new);
        cS = c_new; hprev = h_new;
      }
      if (tid == 0) { S_scal[1] = n + 1; S_scal[2] = 0; }
    }

    sp ^= 1;
    // ---- grid barrier: relaxed LLC atomics, explicit vmcnt ordering, ----
    // ---- NO fences (no L2 writeback/invalidate!)                      ----
    asm volatile("s_waitcnt vmcnt(0)" ::: "memory");  // h stores at LLC
    __syncthreads();
    if (tid == 0) {
      const unsigned g = __hip_atomic_load(&bar[144], __ATOMIC_RELAXED, __HIP_MEMORY_SCOPE_AGENT);
      const int grp = bid & 7;
      const unsigned a = __hip_atomic_fetch_add(&bar[grp * 16], 1u, __ATOMIC_RELAXED, __HIP_MEMORY_SCOPE_AGENT);
      if (a == 15u) {
        __hip_atomic_store(&bar[grp * 16], 0u, __ATOMIC_RELAXED, __HIP_MEMORY_SCOPE_AGENT);
        asm volatile("s_waitcnt vmcnt(0)" ::: "memory");  // reset done before lvl2
        const unsigned a2 = __hip_atomic_fetch_add(&bar[128], 1u, __ATOMIC_RELAXED, __HIP_MEMORY_SCOPE_AGENT);
        if (a2 == 7u) {
          __hip_atomic_store(&bar[128], 0u, __ATOMIC_RELAXED, __HIP_MEMORY_SCOPE_AGENT);
          asm volatile("s_waitcnt vmcnt(0)" ::: "memory");  // reset done before release
          __hip_atomic_store(&bar[144], g + 1u, __ATOMIC_RELAXED, __HIP_MEMORY_SCOPE_AGENT);
        }
      }
      while (__hip_atomic_load(&bar[144], __ATOMIC_RELAXED, __HIP_MEMORY_SCOPE_AGENT) == g)
        __builtin_amdgcn_s_sleep(1);
      asm volatile("" ::: "memory");
    }
    __syncthreads();
  }
}

// ------------------------------------------------------------------
// epilogue: out[b,t,:] = seg-softmax(wh[t,b,:] @ W_out^T + b_out)
__global__ void __launch_bounds__(256)
epi_k(const float* __restrict__ wh, const float* __restrict__ W_oT,
      const float* __restrict__ b_out, float* __restrict__ out) {
  __shared__ float hl[4][512];
  __shared__ float yl[4][66];
  const int tid = threadIdx.x, pair = tid >> 6, lane = tid & 63;
  const int bt = blockIdx.x * 4 + pair;
  const int b = bt >> 9, t = bt & 511;
  const float* hsrc = wh + (size_t)t * 16384 + (size_t)b * 512;
  *(float4*)&hl[pair][lane * 8] = *(const float4*)(hsrc + lane * 8);
  *(float4*)&hl[pair][lane * 8 + 4] = *(const float4*)(hsrc + lane * 8 + 4);
  __syncthreads();
  if (lane < 33) {
    const int o = lane * 2;
    float y0 = b_out[o], y1 = b_out[o + 1];
    const float* hp_ = hl[pair];
    #pragma unroll 8
    for (int k = 0; k < 512; ++k) {
      const float h = hp_[k];
      const float2 w = *(const float2*)(W_oT + k * 66 + o);
      y0 = fmaf(h, w.x, y0);
      y1 = fmaf(h, w.y, y1);
    }
    yl[pair][o] = y0; yl[pair][o + 1] = y1;
  }
  __syncthreads();
  if (tid < 24) {
    const int pr = tid / 6, g = tid - pr * 6;
    const int bt2 = blockIdx.x * 4 + pr;
    const float* yp = &yl[pr][g * 11];
    float m = yp[0];
    for (int u = 1; u < 11; ++u) m = fmaxf(m, yp[u]);
    float e[11], ssum = 0.f;
    for (int u = 0; u < 11; ++u) { e[u] = expf(yp[u] - m); ssum += e[u]; }
    const float inv = 1.0f / ssum;
    float* op = out + (size_t)bt2 * 66 + g * 11;
    for (int u = 0; u < 11; ++u) op[u] = e[u] * inv;
  }
}

// ------------------------------------------------------------------
extern "C" void kernel_launch(void* const* d_in, const int* in_sizes, int n_in,
                              void* d_out, int out_size, void* d_ws, size_t ws_size,
                              hipStream_t stream) {
  (void)in_sizes; (void)n_in; (void)out_size;
  const float* x      = (const float*)d_in[0];
  const float* W_ih   = (const float*)d_in[1];
  const float* W_hh   = (const float*)d_in[2];
  const float* bvec   = (const float*)d_in[3];
  const float* W_out  = (const float*)d_in[4];
  const float* b_out  = (const float*)d_in[5];
  const float* W_halt = (const float*)d_in[6];
  const float* b_halt = (const float*)d_in[7];
  float* out = (float*)d_out;
  float* ws  = (float*)d_ws;

  if (ws_size < (size_t)WS_NEED_BYTES) return;  // visible failure if ws too small

  float* wh    = ws;
  float* hbuf  = ws + 8388608;
  unsigned* bar = (unsigned*)(ws + 8421376);
  float* W_r4  = ws + 8421632;
  float* W_iT  = ws + 9470208;
  float* W_oT  = ws + 9574656;
  float* p_out = out + 1081344;  // B*T*OUT

  hipLaunchKernelGGL(prep_k, dim3(4765), dim3(256), 0, stream,
                     W_ih, W_hh, W_out, W_r4, W_iT, W_oT, hbuf, bar);

  void* args[10];
  args[0] = (void*)&x;      args[1] = (void*)&bvec;  args[2] = (void*)&W_halt;
  args[3] = (void*)&b_halt; args[4] = (void*)&W_r4;  args[5] = (void*)&W_iT;
  args[6] = (void*)&hbuf;   args[7] = (void*)&bar;   args[8] = (void*)&wh;
  args[9] = (void*)&p_out;
  hipLaunchCooperativeKernel((void*)act_main, dim3(NBLK), dim3(256), args, 0, stream);

  hipLaunchKernelGGL(epi_k, dim3(4096), dim3(256), 0, stream, wh, W_oT, b_out, out);
}

// Round 4
// 23559.132 us; speedup vs baseline: 2.4764x; 1.2604x over previous
//
#include <hip/hip_runtime.h>
#include <stdint.h>
#include <stddef.h>

// ACT-LSTM, B=32 T=512 IN=50 H=512 OUT=66, MAX_PONDER=10, EPS=0.01, fp32.
// Round 4: round-3 design (decision-before-GEMM, replicated weighted
// accumulator in LDS, 2 phases/timestep, monotonic tree barrier) with the
// round-3 bug fixed: staged h2 is 16384 floats (64 KB), not 4096. hch is now
// full-size; staging is 16 global_load_lds per wave, one vmcnt drain.
// LDS = 128 KB + small (gfx950 allows 160 KB/workgroup); 1 block/CU.

#define NBLK 128

// ---------------- ws layout (float offsets) ----------------
// wh   : [0, 8388608)            512*32*512  (32 MB)
// hbuf : [8388608, 8421376)      2*16384     h ping-pong (packed [k4][b*4+kl])
// bar  : [8421376, 8421888)      512 uints   monotonic barrier counters
// W_r4 : [8421888, 9470464)      1048576     W_hh repacked [k4][j*16+g*4+kl]
// W_iT : [9470464, 9574912)      51*2048     W_ih repacked [k][j*4+g]
// W_oT : [9574912, 9608704)      512*66      W_out transposed [k][o]
#define WS_NEED_BYTES 38434816ull

__device__ __forceinline__ float sigmf(float v) { return 1.0f / (1.0f + expf(-v)); }

// LLC-coherent (cross-XCD) store: bypass L1+L2 (sc0 sc1).
__device__ __forceinline__ void store_llc(float* p, float v) {
  asm volatile("global_store_dword %0, %1, off sc0 sc1" :: "v"(p), "v"(v) : "memory");
}

#if defined(__has_builtin)
#if __has_builtin(__builtin_amdgcn_global_load_lds)
#define HAVE_GLLDS 1
#endif
#endif

// LLC-coherent global->LDS DMA, 16 B/lane. aux=0x11 = SC0|SC1.
__device__ __forceinline__ void stage_instr(const float* gp, float* lp) {
#ifdef HAVE_GLLDS
  __builtin_amdgcn_global_load_lds((const __attribute__((address_space(1))) unsigned int*)gp,
                                   (__attribute__((address_space(3))) unsigned int*)lp,
                                   16, 0, 0x11);
#else
  float4 tmp;
  asm volatile("global_load_dwordx4 %0, %1, off sc0 sc1" : "=v"(tmp) : "v"(gp) : "memory");
  asm volatile("s_waitcnt vmcnt(0)" ::: "memory");
  *(float4*)(lp + (threadIdx.x & 63) * 4) = tmp;
#endif
}

// ------------------------------------------------------------------
// prep: repack weights (k-major) + zero barrier words. Kernel-end release
// flushes L2 so zeros are visible to act_main's LLC-point atomics.
__global__ void prep_k(const float* __restrict__ W_ih, const float* __restrict__ W_hh,
                       const float* __restrict__ W_out,
                       float* __restrict__ W_r4, float* __restrict__ W_iT,
                       float* __restrict__ W_oT, unsigned* __restrict__ bar) {
  int idx = blockIdx.x * 256 + threadIdx.x;
  if (idx < 1048576) {
    int kl = idx & 3, g = (idx >> 2) & 3, j = (idx >> 4) & 511, k4 = idx >> 13;
    W_r4[idx] = W_hh[(size_t)((g << 9) + j) * 512 + (k4 << 2) + kl];
  }
  int i2 = idx - 1048576;
  if (i2 >= 0 && i2 < 104448) {
    int col = i2 & 2047, k = i2 >> 11;
    int g = col & 3, j = col >> 2;
    W_iT[i2] = W_ih[(size_t)((g << 9) + j) * 51 + k];
  }
  int i3 = idx - 1153024;
  if (i3 >= 0 && i3 < 33792) {
    int k = i3 / 66, o = i3 - k * 66;
    W_oT[i3] = W_out[(size_t)o * 512 + k];
  }
  int i4 = idx - 1186816;
  if (i4 >= 0 && i4 < 512) bar[i4] = 0u;
}

// ------------------------------------------------------------------
// persistent ACT-LSTM: 128 blocks x 256 threads, 4 j-columns/block,
// 2 K=512 dots per thread per phase.
__global__ void __launch_bounds__(256)
act_main(const float* __restrict__ x, const float* __restrict__ bvec,
         const float* __restrict__ W_halt, const float* __restrict__ b_halt,
         const float* __restrict__ W_r4, const float* __restrict__ W_iT,
         float* __restrict__ hbuf, unsigned* __restrict__ bar,
         float* __restrict__ wh, float* __restrict__ p_out) {
  __shared__ float hch[16384];       // staged h2, FULL 64 KB (packed [k4][b*4+kl])
  __shared__ float accL[16384];      // replicated weighted accumulator, 64 KB
  __shared__ float xch[2][256];      // gate exchange
  __shared__ float hps[256];         // halt partials
  __shared__ float S_cum[32], S_p[32], S_nupd[32], S_rem[32];
  __shared__ int S_done[32];
  __shared__ int S_flag[1];          // alldone broadcast

  const int tid = threadIdx.x, bid = blockIdx.x;
  const int b_i = tid >> 3, sub = tid & 7, jl = sub & 1, gate = sub >> 1;
  const int ja = bid * 4 + jl;
  const int offw_a = ja * 16 + gate * 4;      // W_r4 dword offset (j_a); j_b = +32
  const int offi_a = ja * 4 + gate;           // W_iT dword offset (j_a); j_b = +8
  const int wid = tid >> 6, lane4 = (tid & 63) * 4;

  const float bias_a = bvec[gate * 512 + ja];
  const float bias_b = bvec[gate * 512 + ja + 2];
  const float bh = b_halt[0];
  const float wfa = W_iT[50 * 2048 + offi_a];      // first-step flag column
  const float wfb = W_iT[50 * 2048 + offi_a + 8];

  // owner lane (sub<4): owns (b_i, j = 4*bid + sub)
  const int hoidx = bid * 128 + b_i * 4 + sub;

  // init shared state + zero accL (full 16384 floats)
  if (tid < 32) { S_cum[tid] = 0.f; S_done[tid] = 0; S_nupd[tid] = 0.f; S_rem[tid] = 0.f; }
  {
    float4 z = {0.f, 0.f, 0.f, 0.f};
    float4* a4 = (float4*)accL;
    #pragma unroll
    for (int i = 0; i < 16; ++i) a4[tid * 16 + i] = z;
  }
  float cS = 0.f, acc_c = 0.f;
  float gxa, gxb2, gxn_a = 0.f, gxn_b = 0.f;
  {  // x-projection for t=0
    gxa = bias_a; gxb2 = bias_b;
    const float* xr = x + (size_t)b_i * 512 * 50;
    for (int k = 0; k < 50; ++k) {
      const float xv = xr[k];
      gxa  = fmaf(xv, W_iT[k * 2048 + offi_a], gxa);
      gxb2 = fmaf(xv, W_iT[k * 2048 + offi_a + 8], gxb2);
    }
  }
  int t = 0, n = 0, fresh = 1, first = 1;
  unsigned ph = 0;
  __syncthreads();

  while (true) {
    if (!first) {
      // ---- stage h2 of step (t,n) from buf[(ph-1)&1]: 16 KB/wave, one drain ----
      const float* hin = hbuf + (((ph & 1u) ^ 1u)) * 16384;
      {
        const float* gp = hin + wid * 4096 + lane4;
        float* lp = &hch[wid * 4096];
        #pragma unroll
        for (int q = 0; q < 16; ++q) stage_instr(gp + q * 256, lp + q * 256);
      }
      // hide DMA latency: precompute x-projection for t+1
      {
        const int tn = (t + 1 > 511) ? 511 : t + 1;
        gxn_a = bias_a; gxn_b = bias_b;
        const float* xr = x + ((size_t)b_i * 512 + tn) * 50;
        for (int k = 0; k < 50; ++k) {
          const float xv = xr[k];
          gxn_a = fmaf(xv, W_iT[k * 2048 + offi_a], gxn_a);
          gxn_b = fmaf(xv, W_iT[k * 2048 + offi_a + 8], gxn_b);
        }
      }
      asm volatile("s_waitcnt vmcnt(0)" ::: "memory");
      __syncthreads();

      // ---- halt dot for staged step: thread (b_i,sub) covers k4 in [sub*16, +16) ----
      {
        float hp = 0.f;
        const float* hb = hch + b_i * 4;
        #pragma unroll
        for (int i = 0; i < 16; ++i) {
          const int k4 = sub * 16 + i;
          const float4 hv = *(const float4*)(hb + k4 * 128);
          const float4 wv = *(const float4*)(W_halt + k4 * 4);
          hp = fmaf(hv.x, wv.x, fmaf(hv.y, wv.y, fmaf(hv.z, wv.z, fmaf(hv.w, wv.w, hp))));
        }
        hps[tid] = hp;
      }
      __syncthreads();

      // ---- ACT decision for step (t,n) ----
      if (tid < 32) {
        const float* q = hps + tid * 8;
        const float d = ((q[0] + q[1]) + (q[2] + q[3])) + ((q[4] + q[5]) + (q[6] + q[7]));
        const float halt = sigmf(d + bh);
        const float cum = S_cum[tid];
        const int done = S_done[tid];
        const int halted = ((cum + halt) > 0.99f) || (n == 9);
        const float p = done ? 0.f : (halted ? (1.f - cum) : halt);
        S_p[tid] = p;
        S_nupd[tid] += done ? 0.f : 1.f;
        S_rem[tid] += (done || !halted) ? 0.f : (1.f - cum);
        S_cum[tid] = cum + (done ? 0.f : halt);
        S_done[tid] = done | halted;
      }
      __syncthreads();
      if (tid == 0) {
        int ad = 1;
        for (int i = 0; i < 32; ++i) ad &= S_done[i];
        S_flag[0] = ad;
      }
      __syncthreads();
      const int alldone = S_flag[0];

      // ---- accumulate: accL += p_b * h2_staged (b = float4-idx & 31) ----
      {
        float4* a4 = (float4*)accL;
        const float4* h4 = (const float4*)hch;
        #pragma unroll
        for (int i = 0; i < 16; ++i) {
          const int idx = tid * 16 + i;
          const float p = S_p[idx & 31];
          float4 a = a4[idx];
          const float4 h = h4[idx];
          a.x = fmaf(p, h.x, a.x); a.y = fmaf(p, h.y, a.y);
          a.z = fmaf(p, h.z, a.z); a.w = fmaf(p, h.w, a.w);
          a4[idx] = a;
        }
      }
      if (sub < 4) acc_c = fmaf(S_p[b_i], cS, acc_c);  // c2 of staged step = cS
      __syncthreads();

      if (alldone) {  // timestep t complete -> intra-phase carry
        if (sub < 4) {
          wh[(size_t)t * 16384 + (size_t)b_i * 512 + bid * 4 + sub] = accL[hoidx];
          cS = acc_c; acc_c = 0.f;
        }
        if (bid == 0 && tid < 32)
          p_out[(size_t)tid * 512 + t] = S_nupd[tid] + S_rem[tid];
        if (tid < 32) { S_cum[tid] = 0.f; S_done[tid] = 0; S_nupd[tid] = 0.f; S_rem[tid] = 0.f; }
        t += 1; n = 0; fresh = 1;
        gxa = gxn_a; gxb2 = gxn_b;
        if (t == 512) break;       // uniform across blocks
      } else {
        n += 1; fresh = 0;
      }
    }

    // ---- GEMM: input = accL (fresh/carry) or hch (continue) ----
    {
      const float base_a = gxa + (fresh ? wfa : 0.f);
      const float base_b = gxb2 + (fresh ? wfb : 0.f);
      const float* hl = fresh ? accL : hch;
      const float* hb = hl + b_i * 4;
      const float* wb = W_r4 + offw_a;
      float a0 = base_a, a1 = 0.f, a2 = 0.f, a3 = 0.f;
      float b0 = base_b, b1 = 0.f, b2 = 0.f, b3 = 0.f;
      #pragma unroll 8
      for (int u = 0; u < 128; ++u) {
        const float4 h4 = *(const float4*)(hb + u * 128);
        const float4 wa = *(const float4*)(wb + (size_t)u * 8192);
        const float4 wc = *(const float4*)(wb + (size_t)u * 8192 + 32);
        a0 = fmaf(h4.x, wa.x, a0); a1 = fmaf(h4.y, wa.y, a1);
        a2 = fmaf(h4.z, wa.z, a2); a3 = fmaf(h4.w, wa.w, a3);
        b0 = fmaf(h4.x, wc.x, b0); b1 = fmaf(h4.y, wc.y, b1);
        b2 = fmaf(h4.z, wc.z, b2); b3 = fmaf(h4.w, wc.w, b3);
      }
      xch[0][tid] = (a0 + a1) + (a2 + a3);
      xch[1][tid] = (b0 + b1) + (b2 + b3);
    }
    __syncthreads();

    if (fresh) {  // new timestep's accumulator starts at zero (GEMM reads done)
      float4 z = {0.f, 0.f, 0.f, 0.f};
      float4* a4 = (float4*)accL;
      #pragma unroll
      for (int i = 0; i < 16; ++i) a4[tid * 16 + i] = z;
    }
    if (sub < 4) {  // owner of (b_i, 4*bid+sub): gates -> h2, c2; publish h2
      const int jjl = sub & 1;
      const float* arr = (sub < 2) ? xch[0] : xch[1];
      const float gi = arr[b_i * 8 + jjl];
      const float gf = arr[b_i * 8 + 2 + jjl];
      const float gg = arr[b_i * 8 + 4 + jjl];
      const float go = arr[b_i * 8 + 6 + jjl];
      const float c_new = sigmf(gf) * cS + sigmf(gi) * tanhf(gg);
      const float h_new = sigmf(go) * tanhf(c_new);
      store_llc(&hbuf[(ph & 1u) * 16384 + hoidx], h_new);
      cS = c_new;
    }
    first = 0; fresh = 0;

    // ---- grid barrier: monotonic counters, no resets ----
    asm volatile("s_waitcnt vmcnt(0)" ::: "memory");  // h2 stores at LLC
    __syncthreads();
    if (tid == 0) {
      const int grp = bid & 7;
      const unsigned a = __hip_atomic_fetch_add(&bar[grp * 32], 1u, __ATOMIC_RELAXED, __HIP_MEMORY_SCOPE_AGENT);
      if (a == ph * 16u + 15u) {
        const unsigned a2 = __hip_atomic_fetch_add(&bar[256], 1u, __ATOMIC_RELAXED, __HIP_MEMORY_SCOPE_AGENT);
        if (a2 == ph * 8u + 7u)
          __hip_atomic_store(&bar[288], ph + 1u, __ATOMIC_RELAXED, __HIP_MEMORY_SCOPE_AGENT);
      }
      while (__hip_atomic_load(&bar[288], __ATOMIC_RELAXED, __HIP_MEMORY_SCOPE_AGENT) < ph + 1u)
        __builtin_amdgcn_s_sleep(1);
    }
    __syncthreads();
    ph += 1;
  }
}

// ------------------------------------------------------------------
// epilogue: out[b,t,:] = seg-softmax(wh[t,b,:] @ W_out^T + b_out)
__global__ void __launch_bounds__(256)
epi_k(const float* __restrict__ wh, const float* __restrict__ W_oT,
      const float* __restrict__ b_out, float* __restrict__ out) {
  __shared__ float hl[4][512];
  __shared__ float yl[4][66];
  const int tid = threadIdx.x, pair = tid >> 6, lane = tid & 63;
  const int bt = blockIdx.x * 4 + pair;
  const int b = bt >> 9, t = bt & 511;
  const float* hsrc = wh + (size_t)t * 16384 + (size_t)b * 512;
  *(float4*)&hl[pair][lane * 8] = *(const float4*)(hsrc + lane * 8);
  *(float4*)&hl[pair][lane * 8 + 4] = *(const float4*)(hsrc + lane * 8 + 4);
  __syncthreads();
  if (lane < 33) {
    const int o = lane * 2;
    float y0 = b_out[o], y1 = b_out[o + 1];
    const float* hp_ = hl[pair];
    #pragma unroll 8
    for (int k = 0; k < 512; ++k) {
      const float h = hp_[k];
      const float2 w = *(const float2*)(W_oT + k * 66 + o);
      y0 = fmaf(h, w.x, y0);
      y1 = fmaf(h, w.y, y1);
    }
    yl[pair][o] = y0; yl[pair][o + 1] = y1;
  }
  __syncthreads();
  if (tid < 24) {
    const int pr = tid / 6, g = tid - pr * 6;
    const int bt2 = blockIdx.x * 4 + pr;
    const float* yp = &yl[pr][g * 11];
    float m = yp[0];
    for (int u = 1; u < 11; ++u) m = fmaxf(m, yp[u]);
    float e[11], ssum = 0.f;
    for (int u = 0; u < 11; ++u) { e[u] = expf(yp[u] - m); ssum += e[u]; }
    const float inv = 1.0f / ssum;
    float* op = out + (size_t)bt2 * 66 + g * 11;
    for (int u = 0; u < 11; ++u) op[u] = e[u] * inv;
  }
}

// ------------------------------------------------------------------
extern "C" void kernel_launch(void* const* d_in, const int* in_sizes, int n_in,
                              void* d_out, int out_size, void* d_ws, size_t ws_size,
                              hipStream_t stream) {
  (void)in_sizes; (void)n_in; (void)out_size;
  const float* x      = (const float*)d_in[0];
  const float* W_ih   = (const float*)d_in[1];
  const float* W_hh   = (const float*)d_in[2];
  const float* bvec   = (const float*)d_in[3];
  const float* W_out  = (const float*)d_in[4];
  const float* b_out  = (const float*)d_in[5];
  const float* W_halt = (const float*)d_in[6];
  const float* b_halt = (const float*)d_in[7];
  float* out = (float*)d_out;
  float* ws  = (float*)d_ws;

  if (ws_size < (size_t)WS_NEED_BYTES) return;  // visible failure if ws too small

  float* wh     = ws;
  float* hbuf   = ws + 8388608;
  unsigned* bar = (unsigned*)(ws + 8421376);
  float* W_r4   = ws + 8421888;
  float* W_iT   = ws + 9470464;
  float* W_oT   = ws + 9574912;
  float* p_out  = out + 1081344;  // B*T*OUT

  hipLaunchKernelGGL(prep_k, dim3(4638), dim3(256), 0, stream,
                     W_ih, W_hh, W_out, W_r4, W_iT, W_oT, bar);

  void* args[10];
  args[0] = (void*)&x;      args[1] = (void*)&bvec;  args[2] = (void*)&W_halt;
  args[3] = (void*)&b_halt; args[4] = (void*)&W_r4;  args[5] = (void*)&W_iT;
  args[6] = (void*)&hbuf;   args[7] = (void*)&bar;   args[8] = (void*)&wh;
  args[9] = (void*)&p_out;
  hipLaunchCooperativeKernel((void*)act_main, dim3(NBLK), dim3(256), args, 0, stream);

  hipLaunchKernelGGL(epi_k, dim3(4096), dim3(256), 0, stream, wh, W_oT, b_out, out);
}

// Round 5
// 15927.318 us; speedup vs baseline: 3.6629x; 1.4792x over previous
//
#include <hip/hip_runtime.h>
#include <stdint.h>
#include <stddef.h>

// ACT-LSTM, B=32 T=512 IN=50 H=512 OUT=66, MAX_PONDER=10, EPS=0.01, fp32.
// Round 5: round-4 design with LDS bank conflicts eliminated:
//  - accumulate loop reindexed idx=i*256+tid (was tid*16+i: 64-way conflicts,
//    1.8e9 SQ_LDS_BANK_CONFLICT = ~5.7us/phase of serialization)
//  - n==0 accumulate overwrites (fold zero pass into first accumulate)
//  - halt dot uses the same conflict-free per-lane-contiguous pattern
//  - ballot-based alldone; conditional carry sync; s_sleep(2) spin

#define NBLK 128

// ---------------- ws layout (float offsets) ----------------
// wh   : [0, 8388608)            512*32*512  (32 MB)
// hbuf : [8388608, 8421376)      2*16384     h ping-pong (packed [k4][b*4+kl])
// bar  : [8421376, 8421888)      512 uints   monotonic barrier counters
// W_r4 : [8421888, 9470464)      1048576     W_hh repacked [k4][j*16+g*4+kl]
// W_iT : [9470464, 9574912)      51*2048     W_ih repacked [k][j*4+g]
// W_oT : [9574912, 9608704)      512*66      W_out transposed [k][o]
#define WS_NEED_BYTES 38434816ull

__device__ __forceinline__ float sigmf(float v) { return 1.0f / (1.0f + expf(-v)); }

// LLC-coherent (cross-XCD) store: bypass L1+L2 (sc0 sc1).
__device__ __forceinline__ void store_llc(float* p, float v) {
  asm volatile("global_store_dword %0, %1, off sc0 sc1" :: "v"(p), "v"(v) : "memory");
}

#if defined(__has_builtin)
#if __has_builtin(__builtin_amdgcn_global_load_lds)
#define HAVE_GLLDS 1
#endif
#endif

// LLC-coherent global->LDS DMA, 16 B/lane. aux=0x11 = SC0|SC1.
__device__ __forceinline__ void stage_instr(const float* gp, float* lp) {
#ifdef HAVE_GLLDS
  __builtin_amdgcn_global_load_lds((const __attribute__((address_space(1))) unsigned int*)gp,
                                   (__attribute__((address_space(3))) unsigned int*)lp,
                                   16, 0, 0x11);
#else
  float4 tmp;
  asm volatile("global_load_dwordx4 %0, %1, off sc0 sc1" : "=v"(tmp) : "v"(gp) : "memory");
  asm volatile("s_waitcnt vmcnt(0)" ::: "memory");
  *(float4*)(lp + (threadIdx.x & 63) * 4) = tmp;
#endif
}

// ------------------------------------------------------------------
// prep: repack weights (k-major) + zero barrier words.
__global__ void prep_k(const float* __restrict__ W_ih, const float* __restrict__ W_hh,
                       const float* __restrict__ W_out,
                       float* __restrict__ W_r4, float* __restrict__ W_iT,
                       float* __restrict__ W_oT, unsigned* __restrict__ bar) {
  int idx = blockIdx.x * 256 + threadIdx.x;
  if (idx < 1048576) {
    int kl = idx & 3, g = (idx >> 2) & 3, j = (idx >> 4) & 511, k4 = idx >> 13;
    W_r4[idx] = W_hh[(size_t)((g << 9) + j) * 512 + (k4 << 2) + kl];
  }
  int i2 = idx - 1048576;
  if (i2 >= 0 && i2 < 104448) {
    int col = i2 & 2047, k = i2 >> 11;
    int g = col & 3, j = col >> 2;
    W_iT[i2] = W_ih[(size_t)((g << 9) + j) * 51 + k];
  }
  int i3 = idx - 1153024;
  if (i3 >= 0 && i3 < 33792) {
    int k = i3 / 66, o = i3 - k * 66;
    W_oT[i3] = W_out[(size_t)o * 512 + k];
  }
  int i4 = idx - 1186816;
  if (i4 >= 0 && i4 < 512) bar[i4] = 0u;
}

// ------------------------------------------------------------------
// persistent ACT-LSTM: 128 blocks x 256 threads, 4 j-columns/block,
// 2 K=512 dots per thread per phase.
__global__ void __launch_bounds__(256)
act_main(const float* __restrict__ x, const float* __restrict__ bvec,
         const float* __restrict__ W_halt, const float* __restrict__ b_halt,
         const float* __restrict__ W_r4, const float* __restrict__ W_iT,
         float* __restrict__ hbuf, unsigned* __restrict__ bar,
         float* __restrict__ wh, float* __restrict__ p_out) {
  __shared__ float hch[16384];       // staged h2, 64 KB (packed [k4][b*4+kl])
  __shared__ float accL[16384];      // replicated weighted accumulator, 64 KB
  __shared__ float xch[2][256];      // gate exchange
  __shared__ float hps[256];         // halt partials
  __shared__ float S_cum[32], S_p[32], S_nupd[32], S_rem[32];
  __shared__ int S_flag[1];          // alldone broadcast

  const int tid = threadIdx.x, bid = blockIdx.x;
  const int b_i = tid >> 3, sub = tid & 7, jl = sub & 1, gate = sub >> 1;
  const int ja = bid * 4 + jl;
  const int offw_a = ja * 16 + gate * 4;      // W_r4 dword offset (j_a); j_b = +32
  const int offi_a = ja * 4 + gate;           // W_iT dword offset (j_a); j_b = +8
  const int wid = tid >> 6, lane4 = (tid & 63) * 4;

  const float bias_a = bvec[gate * 512 + ja];
  const float bias_b = bvec[gate * 512 + ja + 2];
  const float bh = b_halt[0];
  const float wfa = W_iT[50 * 2048 + offi_a];      // first-step flag column
  const float wfb = W_iT[50 * 2048 + offi_a + 8];

  // owner lane (sub<4): owns (b_i, j = 4*bid + sub)
  const int hoidx = bid * 128 + b_i * 4 + sub;
  const float4* hch4 = (const float4*)hch;
  float4* acc4 = (float4*)accL;
  const float4* Wq = (const float4*)W_halt;   // [k4] float4 view

  // init shared state + zero accL (t=0's fresh GEMM reads accL as h=0)
  if (tid < 32) { S_cum[tid] = 0.f; S_nupd[tid] = 0.f; S_rem[tid] = 0.f; }
  {
    float4 z = {0.f, 0.f, 0.f, 0.f};
    #pragma unroll
    for (int i = 0; i < 16; ++i) acc4[i * 256 + tid] = z;
  }
  int mydone = 0;                     // per-decision-lane ACT done (tid<32)
  float cS = 0.f, acc_c = 0.f;
  float gxa, gxb2, gxn_a = 0.f, gxn_b = 0.f;
  {  // x-projection for t=0
    gxa = bias_a; gxb2 = bias_b;
    const float* xr = x + (size_t)b_i * 512 * 50;
    for (int k = 0; k < 50; ++k) {
      const float xv = xr[k];
      gxa  = fmaf(xv, W_iT[k * 2048 + offi_a], gxa);
      gxb2 = fmaf(xv, W_iT[k * 2048 + offi_a + 8], gxb2);
    }
  }
  int t = 0, n = 0, fresh = 1, first = 1;
  unsigned ph = 0;
  __syncthreads();

  while (true) {
    if (!first) {
      // ---- stage h2 of step (t,n) from buf[(ph-1)&1]: 16 KB/wave, one drain ----
      const float* hin = hbuf + (((ph & 1u) ^ 1u)) * 16384;
      {
        const float* gp = hin + wid * 4096 + lane4;
        float* lp = &hch[wid * 4096];
        #pragma unroll
        for (int q = 0; q < 16; ++q) stage_instr(gp + q * 256, lp + q * 256);
      }
      // hide DMA latency: precompute x-projection for t+1
      {
        const int tn = (t + 1 > 511) ? 511 : t + 1;
        gxn_a = bias_a; gxn_b = bias_b;
        const float* xr = x + ((size_t)b_i * 512 + tn) * 50;
        for (int k = 0; k < 50; ++k) {
          const float xv = xr[k];
          gxn_a = fmaf(xv, W_iT[k * 2048 + offi_a], gxn_a);
          gxn_b = fmaf(xv, W_iT[k * 2048 + offi_a + 8], gxn_b);
        }
      }
      asm volatile("s_waitcnt vmcnt(0)" ::: "memory");
      __syncthreads();

      // ---- halt partial: thread covers float4s f = i*256+tid (batch = tid&31),
      //      conflict-free contiguous-by-lane LDS reads ----
      {
        float hp = 0.f;
        #pragma unroll
        for (int i = 0; i < 16; ++i) {
          const int f = i * 256 + tid;
          const float4 hv = hch4[f];
          const float4 wv = Wq[f >> 5];
          hp = fmaf(hv.x, wv.x, fmaf(hv.y, wv.y, fmaf(hv.z, wv.z, fmaf(hv.w, wv.w, hp))));
        }
        hps[tid] = hp;
      }
      __syncthreads();

      // ---- ACT decision for step (t,n); ballot for alldone ----
      if (tid < 64) {
        int vote = 1;
        if (tid < 32) {
          float d = 0.f;
          #pragma unroll
          for (int r = 0; r < 8; ++r) d += hps[tid + 32 * r];  // distinct banks
          const float halt = sigmf(d + bh);
          const float cum = S_cum[tid];
          const int done = mydone;
          const int halted = ((cum + halt) > 0.99f) || (n == 9);
          S_p[tid] = done ? 0.f : (halted ? (1.f - cum) : halt);
          S_nupd[tid] += done ? 0.f : 1.f;
          S_rem[tid] += (done || !halted) ? 0.f : (1.f - cum);
          S_cum[tid] = cum + (done ? 0.f : halt);
          mydone = done | halted;
          vote = mydone;
        }
        const unsigned long long bal = __ballot(vote);
        if (tid == 0) S_flag[0] = (bal == ~0ull) ? 1 : 0;
      }
      __syncthreads();
      const int alldone = S_flag[0];

      // ---- accumulate: accL (+)= p_b * h2_staged, conflict-free indexing;
      //      n==0 overwrites (folds the zero pass) ----
      {
        const float p_t = S_p[tid & 31];
        if (n == 0) {
          #pragma unroll
          for (int i = 0; i < 16; ++i) {
            const int idx = i * 256 + tid;
            const float4 h = hch4[idx];
            float4 a;
            a.x = p_t * h.x; a.y = p_t * h.y; a.z = p_t * h.z; a.w = p_t * h.w;
            acc4[idx] = a;
          }
        } else {
          #pragma unroll
          for (int i = 0; i < 16; ++i) {
            const int idx = i * 256 + tid;
            float4 a = acc4[idx];
            const float4 h = hch4[idx];
            a.x = fmaf(p_t, h.x, a.x); a.y = fmaf(p_t, h.y, a.y);
            a.z = fmaf(p_t, h.z, a.z); a.w = fmaf(p_t, h.w, a.w);
            acc4[idx] = a;
          }
        }
      }
      if (sub < 4) acc_c = fmaf(S_p[b_i], cS, acc_c);  // c2 of staged step = cS

      if (alldone) {  // timestep t complete -> intra-phase carry
        __syncthreads();             // accL writes visible (GEMM + wh read it)
        if (sub < 4) {
          wh[(size_t)t * 16384 + (size_t)b_i * 512 + bid * 4 + sub] = accL[hoidx];
          cS = acc_c; acc_c = 0.f;
        }
        if (bid == 0 && tid < 32)
          p_out[(size_t)tid * 512 + t] = S_nupd[tid] + S_rem[tid];
        if (tid < 32) { S_cum[tid] = 0.f; S_nupd[tid] = 0.f; S_rem[tid] = 0.f; }
        mydone = 0;
        t += 1; n = 0; fresh = 1;
        gxa = gxn_a; gxb2 = gxn_b;
        if (t == 512) break;         // uniform across blocks
      } else {
        n += 1; fresh = 0;
      }
    }

    // ---- GEMM: input = accL (fresh/carry) or hch (continue) ----
    {
      const float base_a = gxa + (fresh ? wfa : 0.f);
      const float base_b = gxb2 + (fresh ? wfb : 0.f);
      const float* hl = fresh ? accL : hch;
      const float* hb = hl + b_i * 4;
      const float* wb = W_r4 + offw_a;
      float a0 = base_a, a1 = 0.f, a2 = 0.f, a3 = 0.f;
      float b0 = base_b, b1 = 0.f, b2 = 0.f, b3 = 0.f;
      #pragma unroll 8
      for (int u = 0; u < 128; ++u) {
        const float4 h4 = *(const float4*)(hb + u * 128);   // 8-lane broadcast, conflict-free
        const float4 wa = *(const float4*)(wb + (size_t)u * 8192);
        const float4 wc = *(const float4*)(wb + (size_t)u * 8192 + 32);
        a0 = fmaf(h4.x, wa.x, a0); a1 = fmaf(h4.y, wa.y, a1);
        a2 = fmaf(h4.z, wa.z, a2); a3 = fmaf(h4.w, wa.w, a3);
        b0 = fmaf(h4.x, wc.x, b0); b1 = fmaf(h4.y, wc.y, b1);
        b2 = fmaf(h4.z, wc.z, b2); b3 = fmaf(h4.w, wc.w, b3);
      }
      xch[0][tid] = (a0 + a1) + (a2 + a3);
      xch[1][tid] = (b0 + b1) + (b2 + b3);
    }
    __syncthreads();

    if (sub < 4) {  // owner of (b_i, 4*bid+sub): gates -> h2, c2; publish h2
      const int jjl = sub & 1;
      const float* arr = (sub < 2) ? xch[0] : xch[1];
      const float gi = arr[b_i * 8 + jjl];
      const float gf = arr[b_i * 8 + 2 + jjl];
      const float gg = arr[b_i * 8 + 4 + jjl];
      const float go = arr[b_i * 8 + 6 + jjl];
      const float c_new = sigmf(gf) * cS + sigmf(gi) * tanhf(gg);
      const float h_new = sigmf(go) * tanhf(c_new);
      store_llc(&hbuf[(ph & 1u) * 16384 + hoidx], h_new);
      cS = c_new;
    }
    first = 0; fresh = 0;

    // ---- grid barrier: monotonic counters, no resets ----
    asm volatile("s_waitcnt vmcnt(0)" ::: "memory");  // h2 stores at LLC
    __syncthreads();
    if (tid == 0) {
      const int grp = bid & 7;
      const unsigned a = __hip_atomic_fetch_add(&bar[grp * 32], 1u, __ATOMIC_RELAXED, __HIP_MEMORY_SCOPE_AGENT);
      if (a == ph * 16u + 15u) {
        const unsigned a2 = __hip_atomic_fetch_add(&bar[256], 1u, __ATOMIC_RELAXED, __HIP_MEMORY_SCOPE_AGENT);
        if (a2 == ph * 8u + 7u)
          __hip_atomic_store(&bar[288], ph + 1u, __ATOMIC_RELAXED, __HIP_MEMORY_SCOPE_AGENT);
      }
      while (__hip_atomic_load(&bar[288], __ATOMIC_RELAXED, __HIP_MEMORY_SCOPE_AGENT) < ph + 1u)
        __builtin_amdgcn_s_sleep(2);
    }
    __syncthreads();
    ph += 1;
  }
}

// ------------------------------------------------------------------
// epilogue: out[b,t,:] = seg-softmax(wh[t,b,:] @ W_out^T + b_out)
__global__ void __launch_bounds__(256)
epi_k(const float* __restrict__ wh, const float* __restrict__ W_oT,
      const float* __restrict__ b_out, float* __restrict__ out) {
  __shared__ float hl[4][512];
  __shared__ float yl[4][66];
  const int tid = threadIdx.x, pair = tid >> 6, lane = tid & 63;
  const int bt = blockIdx.x * 4 + pair;
  const int b = bt >> 9, t = bt & 511;
  const float* hsrc = wh + (size_t)t * 16384 + (size_t)b * 512;
  *(float4*)&hl[pair][lane * 8] = *(const float4*)(hsrc + lane * 8);
  *(float4*)&hl[pair][lane * 8 + 4] = *(const float4*)(hsrc + lane * 8 + 4);
  __syncthreads();
  if (lane < 33) {
    const int o = lane * 2;
    float y0 = b_out[o], y1 = b_out[o + 1];
    const float* hp_ = hl[pair];
    #pragma unroll 8
    for (int k = 0; k < 512; ++k) {
      const float h = hp_[k];
      const float2 w = *(const float2*)(W_oT + k * 66 + o);
      y0 = fmaf(h, w.x, y0);
      y1 = fmaf(h, w.y, y1);
    }
    yl[pair][o] = y0; yl[pair][o + 1] = y1;
  }
  __syncthreads();
  if (tid < 24) {
    const int pr = tid / 6, g = tid - pr * 6;
    const int bt2 = blockIdx.x * 4 + pr;
    const float* yp = &yl[pr][g * 11];
    float m = yp[0];
    for (int u = 1; u < 11; ++u) m = fmaxf(m, yp[u]);
    float e[11], ssum = 0.f;
    for (int u = 0; u < 11; ++u) { e[u] = expf(yp[u] - m); ssum += e[u]; }
    const float inv = 1.0f / ssum;
    float* op = out + (size_t)bt2 * 66 + g * 11;
    for (int u = 0; u < 11; ++u) op[u] = e[u] * inv;
  }
}

// ------------------------------------------------------------------
extern "C" void kernel_launch(void* const* d_in, const int* in_sizes, int n_in,
                              void* d_out, int out_size, void* d_ws, size_t ws_size,
                              hipStream_t stream) {
  (void)in_sizes; (void)n_in; (void)out_size;
  const float* x      = (const float*)d_in[0];
  const float* W_ih   = (const float*)d_in[1];
  const float* W_hh   = (const float*)d_in[2];
  const float* bvec   = (const float*)d_in[3];
  const float* W_out  = (const float*)d_in[4];
  const float* b_out  = (const float*)d_in[5];
  const float* W_halt = (const float*)d_in[6];
  const float* b_halt = (const float*)d_in[7];
  float* out = (float*)d_out;
  float* ws  = (float*)d_ws;

  if (ws_size < (size_t)WS_NEED_BYTES) return;  // visible failure if ws too small

  float* wh     = ws;
  float* hbuf   = ws + 8388608;
  unsigned* bar = (unsigned*)(ws + 8421376);
  float* W_r4   = ws + 8421888;
  float* W_iT   = ws + 9470464;
  float* W_oT   = ws + 9574912;
  float* p_out  = out + 1081344;  // B*T*OUT

  hipLaunchKernelGGL(prep_k, dim3(4638), dim3(256), 0, stream,
                     W_ih, W_hh, W_out, W_r4, W_iT, W_oT, bar);

  void* args[10];
  args[0] = (void*)&x;      args[1] = (void*)&bvec;  args[2] = (void*)&W_halt;
  args[3] = (void*)&b_halt; args[4] = (void*)&W_r4;  args[5] = (void*)&W_iT;
  args[6] = (void*)&hbuf;   args[7] = (void*)&bar;   args[8] = (void*)&wh;
  args[9] = (void*)&p_out;
  hipLaunchCooperativeKernel((void*)act_main, dim3(NBLK), dim3(256), args, 0, stream);

  hipLaunchKernelGGL(epi_k, dim3(4096), dim3(256), 0, stream, wh, W_oT, b_out, out);
}